// Round 1
// 231.036 us; speedup vs baseline: 1.0227x; 1.0227x over previous
//
#include <hip/hip_runtime.h>
#include <hip/hip_bf16.h>

#define Bdim 2
#define Tdim 2048
#define Cdim 2048
#define Hn   16
// HS = 128, ROT = 64, 32 freqs

using bf16x8 = __attribute__((ext_vector_type(8))) short;
using f32x4  = __attribute__((ext_vector_type(4))) float;
using f32x16 = __attribute__((ext_vector_type(16))) float;
typedef __hip_bfloat16 bf16;

#define VMWAIT(n) asm volatile("s_waitcnt vmcnt(" #n ")" ::: "memory")
#define CROW(r, hi) (((r) & 3) + 8 * ((r) >> 2) + 4 * (hi))
// 1/sqrt(128) * log2(e): attention scores land in exp2 units
#define QS2 ((float)(0.08838834764831845 * 1.4426950408889634))
#define THR2 11.5415603f   // 8 * log2(e)

__device__ __forceinline__ void load_lds16(const void* g, void* l) {
  __builtin_amdgcn_global_load_lds(
      (const __attribute__((address_space(1))) void*)g,
      (__attribute__((address_space(3))) void*)l, 16, 0, 0);
}

__device__ __forceinline__ float bf2f(unsigned short u) {
  union { unsigned int i; float f; } x; x.i = ((unsigned int)u) << 16; return x.f;
}
__device__ __forceinline__ unsigned short f2bf(float f) {
  bf16 h = __float2bfloat16(f); return *(unsigned short*)&h;
}
__device__ __forceinline__ unsigned cvtpk(float lo, float hi) {
  unsigned r;
  asm volatile("v_cvt_pk_bf16_f32 %0, %1, %2" : "=v"(r) : "v"(lo), "v"(hi));
  return r;
}

// ---------------- fused f32 -> bf16 convert (x + 4 weights) ----------------
__global__ __launch_bounds__(256) void cvt_all(const float* __restrict__ x,
                                               const float* __restrict__ w0,
                                               const float* __restrict__ w1,
                                               const float* __restrict__ w2,
                                               const float* __restrict__ w3,
                                               bf16* __restrict__ dx,
                                               bf16* __restrict__ d0,
                                               bf16* __restrict__ d1,
                                               bf16* __restrict__ d2,
                                               bf16* __restrict__ d3) {
  const int NX = (Bdim * Tdim * Cdim) / 4;  // 2^21
  const int NW = (Cdim * Cdim) / 4;         // 2^20
  int i = blockIdx.x * 256 + threadIdx.x;
  int stride = gridDim.x * 256;
  for (; i < NX + 4 * NW; i += stride) {
    const float* s; bf16* d; int j;
    if (i < NX) { s = x; d = dx; j = i; }
    else {
      int k = i - NX;
      int wsel = k >> 20;
      j = k & (NW - 1);
      s = wsel == 0 ? w0 : wsel == 1 ? w1 : wsel == 2 ? w2 : w3;
      d = wsel == 0 ? d0 : wsel == 1 ? d1 : wsel == 2 ? d2 : d3;
    }
    float4 v = ((const float4*)s)[j];
    ushort4 o;
    o.x = f2bf(v.x); o.y = f2bf(v.y); o.z = f2bf(v.z); o.w = f2bf(v.w);
    ((ushort4*)d)[j] = o;
  }
}

// ---------------- RoPE tables (f64-accurate, interleaved cos/sin) ----------------
__global__ __launch_bounds__(256) void rope_tables_k(float2* __restrict__ cst) {
  int idx = blockIdx.x * blockDim.x + threadIdx.x;
  if (idx >= Tdim * 32) return;
  int t = idx >> 5, i = idx & 31;
  double f = pow(10000.0, -(double)i / 32.0);
  double ang = (double)t * f;
  cst[idx] = make_float2((float)cos(ang), (float)sin(ang));
}

// ======== QKV GEMM v2: 256x384 tile, BK=32, 3-deep LDS rotation, 8 waves ========
// 32x32x16 MFMA (layout verified by attn kernel: A/B lane l holds row l&31,
// k = 8*(l>>5)+e; C/D row = CROW(r,hi), col = l&31).
// Grid = 16 row-tiles x 16 strips = 256 blocks = exactly 1 block/CU.
// LDS per tile: A[256][32]+B[384][32] bf16 = 40960 B, x3 buffers = 122880 B.
// Rows are 64B (4 slots of 16B); slot swizzle = slot ^ ((row>>1)&3), applied
// on pre-swizzled global source (linear gload_lds dest) and on ds_read.
// Epilogue: bias + RoPE(Q*QS2, K) + V transpose. Head-dim-block parity
// hb = (wc*3+n)&3: 0=rot-low (partner n+1, except wc2-n2 whose partner is
// wc3-n0 via 32KB LDS stash), 1=rot-high (stored by partner), 2/3=pass.
__global__ __launch_bounds__(512, 2) void gemmQKV(
    const bf16* __restrict__ A, const bf16* __restrict__ Wcat,
    const float* __restrict__ b0, const float* __restrict__ b1, const float* __restrict__ b2,
    bf16* __restrict__ oq, bf16* __restrict__ ok, bf16* __restrict__ vt,
    const float2* __restrict__ cst) {
  extern __shared__ char lds[];
  const int tid = threadIdx.x, lane = tid & 63, wid = tid >> 6;
  const int l31 = lane & 31, hi = lane >> 5;
  const int wr = wid >> 2, wc = wid & 3;   // 2 row-waves x 4 col-waves
  const int wbase = wid * 1024;

  const int q8 = gridDim.x >> 3;           // 32
  const int swz = ((int)blockIdx.x & 7) * q8 + ((int)blockIdx.x >> 3);
  const int bm = (swz >> 4) * 256;
  const int strip = swz & 15;

  // staging map: thread -> (row = tid>>2 within 128-row chunk, slot = tid&3)
  const int rS = tid >> 2, sS = tid & 3;
  const int ssw = (sS ^ ((rS >> 1) & 3)) << 3;   // pre-swizzled k-offset (elems)
  const bf16* thrA = A + (size_t)(bm + rS) * 2048 + ssw;
  const bf16* thrB = Wcat + (size_t)(strip * 384 + rS) * 2048 + ssw;

#define SA(T, DB) { load_lds16(thrA + (T) * 32, (DB) + wbase);                              \
                    load_lds16(thrA + (size_t)128 * 2048 + (T) * 32, (DB) + 8192 + wbase); }
#define SB(T, DB) { load_lds16(thrB + (T) * 32, (DB) + 16384 + wbase);                      \
                    load_lds16(thrB + (size_t)128 * 2048 + (T) * 32, (DB) + 24576 + wbase); \
                    load_lds16(thrB + (size_t)256 * 2048 + (T) * 32, (DB) + 32768 + wbase); }

  f32x16 acc[4][3] = {};
  bf16x8 afr[4], bfr[3];
  const int q2 = (l31 >> 1) & 3;
  const int aoff = (wr * 128 + l31) * 64;          // A rows: wr*128 + m*32 + l31
  const int boff = 16384 + (wc * 96 + l31) * 64;   // B rows: wc*96 + n*32 + l31
  const int sl0 = (hi ^ q2) << 4;                  // k16 step 0 slot byte
  const int sl1 = sl0 ^ 32;                        // k16 step 1

#define READF(PB, SL)                                                        \
  {                                                                          \
    const char* _p = (PB);                                                   \
    _Pragma("unroll")                                                        \
    for (int m_ = 0; m_ < 4; ++m_)                                           \
      afr[m_] = *(const bf16x8*)(_p + aoff + m_ * 2048 + (SL));              \
    _Pragma("unroll")                                                        \
    for (int n_ = 0; n_ < 3; ++n_)                                           \
      bfr[n_] = *(const bf16x8*)(_p + boff + n_ * 2048 + (SL));              \
  }

#define MF12()                                                               \
  __builtin_amdgcn_s_setprio(1);                                             \
  _Pragma("unroll")                                                          \
  for (int m_ = 0; m_ < 4; ++m_)                                             \
    _Pragma("unroll")                                                        \
    for (int n_ = 0; n_ < 3; ++n_)                                           \
      acc[m_][n_] = __builtin_amdgcn_mfma_f32_32x32x16_bf16(                 \
          afr[m_], bfr[n_], acc[m_][n_], 0, 0, 0);                           \
  __builtin_amdgcn_s_setprio(0);

#define BARS()                                                               \
  __builtin_amdgcn_s_barrier();                                              \
  asm volatile("s_waitcnt lgkmcnt(0)" ::: "memory");                         \
  __builtin_amdgcn_sched_barrier(0);

#define BARE() __builtin_amdgcn_s_barrier();

  // prologue: stage tiles 0,1 (5 loads each); confirm tile 0; barrier.
  SA(0, lds); SB(0, lds);
  SA(1, lds + 40960); SB(1, lds + 40960);
  VMWAIT(5);
  __builtin_amdgcn_s_barrier();

  const char* rb = lds;            // read buffer  = buf[t%3]
  char* sb = lds + 81920;          // stage buffer = buf[(t+2)%3]
  const int NT = 64;               // K/32

  for (int t = 0; t < NT - 2; ++t) {
    READF(rb, sl0);
    SA(t + 2, sb);
    BARS(); MF12(); BARE();
    READF(rb, sl1);
    SB(t + 2, sb);
    VMWAIT(5);                     // confirm tile t+1 fully staged
    BARS(); MF12(); BARE();
    rb = (rb == lds + 81920) ? lds : rb + 40960;
    sb = (sb == lds + 81920) ? lds : sb + 40960;
  }
  {  // t = NT-2: no staging; confirm last tile
    READF(rb, sl0);
    BARS(); MF12(); BARE();
    READF(rb, sl1);
    VMWAIT(0);
    BARS(); MF12(); BARE();
    rb = (rb == lds + 81920) ? lds : rb + 40960;
  }
  {  // t = NT-1
    READF(rb, sl0);
    BARS(); MF12(); BARE();
    READF(rb, sl1);
    BARS(); MF12(); BARE();
  }

  // ---------------- epilogue: bias + RoPE(Q,K) + V transpose ----------------
  __syncthreads();
  // wc==3 stashes its n=0 block (acc+bias) for wc==2's cross-wave rope partner
  if (wc == 3) {
    const int col0 = strip * 384 + 288;
    const int mat = col0 >> 11;
    if (mat < 2) {
      const int oc0 = col0 & 2047;
      const float bv = (mat == 0 ? b0 : b1)[oc0 + l31];
      #pragma unroll
      for (int m = 0; m < 4; ++m)
        #pragma unroll
        for (int g = 0; g < 4; ++g) {
          f32x4 v;
          v[0] = acc[m][0][4 * g + 0] + bv;
          v[1] = acc[m][0][4 * g + 1] + bv;
          v[2] = acc[m][0][4 * g + 2] + bv;
          v[3] = acc[m][0][4 * g + 3] + bv;
          *(f32x4*)(lds + (((((wr * 4 + m) * 4 + g) * 2 + hi) * 32) + l31) * 16) = v;
        }
    }
  }
  __syncthreads();

  #pragma unroll
  for (int m = 0; m < 4; ++m) {
    const int rowb = bm + wr * 128 + m * 32;       // + CROW(r,hi)
    const int bb = rowb >> 11, tb = rowb & 2047;
    #pragma unroll
    for (int n = 0; n < 3; ++n) {
      const int col0 = strip * 384 + wc * 96 + n * 32;
      const int mat = col0 >> 11;
      const int oc0 = col0 & 2047;
      const float bv = (mat == 0 ? b0 : mat == 1 ? b1 : b2)[oc0 + l31];
      if (mat == 2) {
        // V transpose: vt[(b*16+h)*128 + d][t]
        const int hh = oc0 >> 7;
        bf16* dst = vt + ((size_t)((bb * 16 + hh) * 128 + (oc0 & 127) + l31)) * 2048 + tb;
        #pragma unroll
        for (int g = 0; g < 4; ++g) {
          ushort4 pk;
          pk.x = f2bf(acc[m][n][4 * g + 0] + bv);
          pk.y = f2bf(acc[m][n][4 * g + 1] + bv);
          pk.z = f2bf(acc[m][n][4 * g + 2] + bv);
          pk.w = f2bf(acc[m][n][4 * g + 3] + bv);
          *(ushort4*)(dst + g * 8 + hi * 4) = pk;
        }
      } else {
        const float qs = (mat == 0) ? QS2 : 1.0f;
        bf16* obf = (mat == 0) ? oq : ok;
        const int hb = (wc * 3 + n) & 3;
        if (hb == 0) {
          if (wc == 2 && n == 2) {
            // rot-low, cross-wave partner from stash (bias already applied)
            #pragma unroll
            for (int g = 0; g < 4; ++g) {
              f32x4 ux = *(const f32x4*)(lds + (((((wr * 4 + m) * 4 + g) * 2 + hi) * 32) + l31) * 16);
              #pragma unroll
              for (int j = 0; j < 4; ++j) {
                const int r = 4 * g + j;
                const int row = rowb + j + 8 * g + 4 * hi;
                const int tt = row & 2047;
                float2 cs = cst[tt * 32 + l31];
                float u0 = acc[m][n][r] + bv;
                float u1 = ux[j];
                obf[(size_t)row * 2048 + oc0 + l31] =
                    __float2bfloat16((u0 * cs.x - u1 * cs.y) * qs);
                obf[(size_t)row * 2048 + oc0 + 32 + l31] =
                    __float2bfloat16((u1 * cs.x + u0 * cs.y) * qs);
              }
            }
          } else {
            // rot-low, in-thread partner n+1
            const float bv1 = (mat == 0 ? b0 : b1)[oc0 + 32 + l31];
            #pragma unroll
            for (int r = 0; r < 16; ++r) {
              const int row = rowb + (r & 3) + 8 * (r >> 2) + 4 * hi;
              const int tt = row & 2047;
              float2 cs = cst[tt * 32 + l31];
              float u0 = acc[m][n][r] + bv;
              float u1 = acc[m][n + 1][r] + bv1;
              obf[(size_t)row * 2048 + oc0 + l31] =
                  __float2bfloat16((u0 * cs.x - u1 * cs.y) * qs);
              obf[(size_t)row * 2048 + oc0 + 32 + l31] =
                  __float2bfloat16((u1 * cs.x + u0 * cs.y) * qs);
            }
          }
        } else if (hb >= 2) {
          // pass-through
          #pragma unroll
          for (int r = 0; r < 16; ++r) {
            const int row = rowb + (r & 3) + 8 * (r >> 2) + 4 * hi;
            obf[(size_t)row * 2048 + oc0 + l31] =
                __float2bfloat16((acc[m][n][r] + bv) * qs);
          }
        }
        // hb == 1: rot-high, stored by the partner handler
      }
    }
  }
#undef SA
#undef SB
#undef READF
#undef MF12
#undef BARS
#undef BARE
}

// ======== Wo GEMM: 128x256, BK=64, 8-phase m201-style (proven) ========
__global__ __launch_bounds__(512, 2) void gemmWo(
    const bf16* __restrict__ A, const bf16* __restrict__ W0,
    const float* __restrict__ b0, float* __restrict__ out, int K, int nby) {
  extern __shared__ char lds[];
  const int tid = threadIdx.x, lane = tid & 63, wid = tid >> 6;
  const int l15 = lane & 15, lhi = lane >> 4;
  const int wr = wid >> 2, wc = wid & 3;
  const int fb = (wc & 1) | ((wc >> 1) << 2);

  const int q8 = gridDim.x >> 3;
  const int swz = ((int)blockIdx.x & 7) * q8 + ((int)blockIdx.x >> 3);
  const int bm = (swz / nby) * 128, bn = (swz % nby) * 256;
  const bf16* Asrc = A + (size_t)bm * K;
  const bf16* Wsrc = W0 + (size_t)bn * K;

  const bf16 *sA0, *sA1, *sB00, *sB01, *sB10, *sB11;
  {
    int c = tid, r = c >> 3, sl = c & 7;
    size_t off = (size_t)r * K + ((sl ^ (r & 7)) << 3);
    sA0 = Asrc + off;
    sA1 = Asrc + (size_t)64 * K + off;
    sB00 = Wsrc + off;
    sB10 = Wsrc + (size_t)128 * K + off;
  }
  {
    int c = 512 + tid, r = c >> 3, sl = c & 7;
    size_t off = (size_t)r * K + ((sl ^ (r & 7)) << 3);
    sB01 = Wsrc + off;
    sB11 = Wsrc + (size_t)128 * K + off;
  }
  const int ldsA = wid * 1024;

#define SA0(t) load_lds16(sA0 + (t) * 64, lds + ((t) & 1) * 49152 + ldsA)
#define SA1(t) load_lds16(sA1 + (t) * 64, lds + ((t) & 1) * 49152 + 8192 + ldsA)
#define SB0(t) { load_lds16(sB00 + (t) * 64, lds + ((t) & 1) * 49152 + 16384 + ldsA); \
                 load_lds16(sB01 + (t) * 64, lds + ((t) & 1) * 49152 + 24576 + ldsA); }
#define SB1(t) { load_lds16(sB10 + (t) * 64, lds + ((t) & 1) * 49152 + 32768 + ldsA); \
                 load_lds16(sB11 + (t) * 64, lds + ((t) & 1) * 49152 + 40960 + ldsA); }

  f32x4 acc[4][4] = {};
  const int NT = K / 64;
  const int NI = NT / 2;
  const int asw = (l15 & 7) << 4;
  bf16x8 afr[2][2], bfr0[2][2], bfr1[2][2];

#define READ_A(BASE)                                                            \
  _Pragma("unroll")                                                             \
  for (int ii = 0; ii < 2; ++ii)                                                \
    _Pragma("unroll")                                                           \
    for (int kk = 0; kk < 2; ++kk)                                              \
      afr[ii][kk] = *(const bf16x8*)((BASE) + (wr * 32 + ii * 16 + l15) * 128   \
                                     + ((kk * 64 + lhi * 16) ^ asw));

#define READ_B(BASE, DST)                                                       \
  _Pragma("unroll")                                                             \
  for (int j = 0; j < 2; ++j)                                                   \
    _Pragma("unroll")                                                           \
    for (int kk = 0; kk < 2; ++kk)                                              \
      DST[j][kk] = *(const bf16x8*)((BASE) + ((fb + 2 * j) * 16 + l15) * 128    \
                                    + ((kk * 64 + lhi * 16) ^ asw));

#define MFMA_Q(MH, NH, BF)                                                      \
  __builtin_amdgcn_s_setprio(1);                                                \
  _Pragma("unroll")                                                             \
  for (int ii = 0; ii < 2; ++ii)                                                \
    _Pragma("unroll")                                                           \
    for (int j = 0; j < 2; ++j)                                                 \
      _Pragma("unroll")                                                         \
      for (int kk = 0; kk < 2; ++kk)                                            \
        acc[(MH) * 2 + ii][(NH) * 2 + j] =                                      \
            __builtin_amdgcn_mfma_f32_16x16x32_bf16(                            \
                afr[ii][kk], BF[j][kk], acc[(MH) * 2 + ii][(NH) * 2 + j], 0, 0, 0); \
  __builtin_amdgcn_s_setprio(0);

#define BAR_IN()                                                                \
  __builtin_amdgcn_s_barrier();                                                 \
  asm volatile("s_waitcnt lgkmcnt(0)" ::: "memory");                            \
  __builtin_amdgcn_sched_barrier(0);

#define BAR_OUT() __builtin_amdgcn_s_barrier();

  SA0(0); SB0(0); SB1(0); SA1(0);
  SA0(1); SB0(1); SB1(1);
  VMWAIT(5);
  __builtin_amdgcn_s_barrier();

  char* const buf0 = lds;
  char* const buf1 = lds + 49152;

  for (int i = 0; i < NI; ++i) {
    const int t0 = 2 * i, t1 = t0 + 1;
    const bool lastI = (i == NI - 1);

    READ_A(buf0);
    READ_B(buf0 + 16384, bfr0);
    SA1(t1);
    BAR_IN(); MFMA_Q(0, 0, bfr0); BAR_OUT();

    READ_B(buf0 + 32768, bfr1);
    if (!lastI) SA0(t0 + 2);
    BAR_IN(); MFMA_Q(0, 1, bfr1); BAR_OUT();

    READ_A(buf0 + 8192);
    if (!lastI) SB0(t0 + 2);
    BAR_IN(); MFMA_Q(1, 0, bfr0); BAR_OUT();

    if (!lastI) { SB1(t0 + 2); VMWAIT(5); } else VMWAIT(0);
    BAR_IN(); MFMA_Q(1, 1, bfr1); BAR_OUT();

    READ_A(buf1);
    READ_B(buf1 + 16384, bfr0);
    if (!lastI) SA1(t0 + 2);
    BAR_IN(); MFMA_Q(0, 0, bfr0); BAR_OUT();

    READ_B(buf1 + 32768, bfr1);
    if (!lastI) SA0(t1 + 2);
    BAR_IN(); MFMA_Q(0, 1, bfr1); BAR_OUT();

    READ_A(buf1 + 8192);
    if (!lastI) SB0(t1 + 2);
    BAR_IN(); MFMA_Q(1, 0, bfr0); BAR_OUT();

    if (!lastI) { SB1(t1 + 2); VMWAIT(5); }
    BAR_IN(); MFMA_Q(1, 1, bfr1); BAR_OUT();
  }

  #pragma unroll
  for (int mi = 0; mi < 4; ++mi) {
    const int row = bm + (mi >> 1) * 64 + wr * 32 + (mi & 1) * 16 + lhi * 4;
    #pragma unroll
    for (int nj = 0; nj < 4; ++nj) {
      const int col = bn + (nj >> 1) * 128 + (fb + 2 * (nj & 1)) * 16 + l15;
      const float bv = b0[col];
      #pragma unroll
      for (int r = 0; r < 4; ++r)
        out[(size_t)(row + r) * 2048 + col] = acc[mi][nj][r] + bv;
    }
  }
#undef SA0
#undef SA1
#undef SB0
#undef SB1
#undef READ_A
#undef READ_B
#undef MFMA_Q
#undef BAR_IN
#undef BAR_OUT
}

// ---------------- Flash attention v6: swapped QK^T, in-reg softmax, exp2 ----------
// Q pre-roped and pre-scaled by QS2 (scores in exp2 units).
__global__ __launch_bounds__(256, 2) void attn_kernel(const bf16* __restrict__ Q,
                                                      const bf16* __restrict__ Kb,
                                                      const bf16* __restrict__ Vt,
                                                      bf16* __restrict__ O) {
  extern __shared__ char lds[];
  const int tid = threadIdx.x, lane = tid & 63, wave = tid >> 6;
  const int l31 = lane & 31, hi = lane >> 5;
  const int hi16 = hi << 4;

  const int bid = blockIdx.x;
  const int half = bid >> 8;
  const int idx = bid & 255;
  const int g = idx >> 5;
  const int qt = half ? g : (15 - g);
  const int bh = idx & 31;
  const int b = bh >> 4, h = bh & 15;
  const size_t bT = (size_t)b * Tdim;

  const int qb = qt * 128 + wave * 32;   // wave's first q row
  const int myq = qb + l31;              // this lane's query

  bf16x8 qf[8];
  {
    const bf16* qrow = Q + (bT + myq) * Cdim + h * 128;
    #pragma unroll
    for (int ds = 0; ds < 8; ++ds)
      qf[ds] = *(const bf16x8*)(qrow + ds * 16 + hi * 8);
  }

  auto stageKV = [&](int kt) {
    const int k0 = kt * 64;
    char* kb = lds + (kt & 1) * 16384;
    char* vb = lds + 32768 + (kt & 1) * 16384;
    #pragma unroll
    for (int i = 0; i < 4; ++i) {
      int cb = i * 256 + wave * 64;
      int c = cb + lane;
      {
        int row = c >> 4, slot = c & 15;
        load_lds16(Kb + (bT + k0 + row) * Cdim + h * 128 + ((slot ^ (row & 7)) << 3),
                   kb + cb * 16);
      }
      {
        int row = c >> 3, slot = c & 7;
        load_lds16(Vt + ((size_t)(bh * 128 + row)) * Tdim + k0 + ((slot ^ (row & 7)) << 3),
                   vb + cb * 16);
      }
    }
  };

  f32x16 o[4] = {};      // o[dblk][reg] = O[qb + CROW(reg,hi)][dblk*32 + l31]
  float mrun = -1e30f, lrun = 0.f;

  const int nt = 2 * (qt + 1);
  stageKV(0);

  for (int kt = 0; kt < nt; ++kt) {
    if (kt + 1 < nt) { stageKV(kt + 1); VMWAIT(8); } else { VMWAIT(0); }
    __syncthreads();
    const char* kbuf = lds + (kt & 1) * 16384;
    const char* vbuf = lds + 32768 + (kt & 1) * 16384;
    const int k0 = kt * 64;

    const bool active = (k0 <= qb + 31);
    if (active) {
      f32x16 s0 = {}, s1 = {};
      const int krow0 = l31, krow1 = 32 + l31;
      const int ksw = (l31 & 7) << 4;
      __builtin_amdgcn_s_setprio(1);
      #pragma unroll
      for (int ds = 0; ds < 8; ++ds) {
        const int boff = (ds * 32 + hi16) ^ ksw;
        bf16x8 kf0 = *(const bf16x8*)(kbuf + krow0 * 256 + boff);
        bf16x8 kf1 = *(const bf16x8*)(kbuf + krow1 * 256 + boff);
        s0 = __builtin_amdgcn_mfma_f32_32x32x16_bf16(kf0, qf[ds], s0, 0, 0, 0);
        s1 = __builtin_amdgcn_mfma_f32_32x32x16_bf16(kf1, qf[ds], s1, 0, 0, 0);
      }
      __builtin_amdgcn_s_setprio(0);

      if (k0 + 63 > qb) {
        #pragma unroll
        for (int r = 0; r < 16; ++r) {
          const int key = k0 + CROW(r, hi);
          if (key > myq)      s0[r] = -1e30f;
          if (key + 32 > myq) s1[r] = -1e30f;
        }
      }

      float mx = s0[0];
      #pragma unroll
      for (int r = 1; r < 16; ++r) mx = fmaxf(mx, s0[r]);
      #pragma unroll
      for (int r = 0; r < 16; ++r) mx = fmaxf(mx, s1[r]);
      mx = fmaxf(mx, __shfl_xor(mx, 32));
      if (!__all(mx <= mrun + THR2)) {
        const float mnew = fmaxf(mrun, mx);
        const float scl = __builtin_amdgcn_exp2f(mrun - mnew);
        lrun *= scl;
        #pragma unroll
        for (int r = 0; r < 16; ++r) {
          const float sr = __shfl(scl, CROW(r, hi));
          o[0][r] *= sr; o[1][r] *= sr; o[2][r] *= sr; o[3][r] *= sr;
        }
        mrun = mnew;
      }
      float p0[16], p1[16];
      float ps = 0.f;
      #pragma unroll
      for (int r = 0; r < 16; ++r) {
        p0[r] = __builtin_amdgcn_exp2f(s0[r] - mrun); ps += p0[r];
        p1[r] = __builtin_amdgcn_exp2f(s1[r] - mrun); ps += p1[r];
      }
      ps += __shfl_xor(ps, 32);
      lrun += ps;

      unsigned u0[8], u1[8];
      #pragma unroll
      for (int gg = 0; gg < 4; ++gg) {
        u0[gg * 2 + 0] = cvtpk(p0[gg * 4 + 0], p0[gg * 4 + 1]);
        u0[gg * 2 + 1] = cvtpk(p0[gg * 4 + 2], p0[gg * 4 + 3]);
        u1[gg * 2 + 0] = cvtpk(p1[gg * 4 + 0], p1[gg * 4 + 1]);
        u1[gg * 2 + 1] = cvtpk(p1[gg * 4 + 2], p1[gg * 4 + 3]);
      }
      bf16x8 paf[4];
      #pragma unroll
      for (int s = 0; s < 2; ++s) {
        const unsigned* us = s ? u1 : u0;
        #pragma unroll
        for (int gp = 0; gp < 2; ++gp) {
          unsigned snd0 = hi ? us[4 * gp + 0] : us[4 * gp + 2];
          unsigned snd1 = hi ? us[4 * gp + 1] : us[4 * gp + 3];
          unsigned rcv0 = __shfl_xor((int)snd0, 32);
          unsigned rcv1 = __shfl_xor((int)snd1, 32);
          union { unsigned w[4]; bf16x8 v; } fr;
          if (hi == 0) {
            fr.w[0] = us[4 * gp + 0]; fr.w[1] = us[4 * gp + 1];
            fr.w[2] = rcv0;           fr.w[3] = rcv1;
          } else {
            fr.w[0] = rcv0;           fr.w[1] = rcv1;
            fr.w[2] = us[4 * gp + 2]; fr.w[3] = us[4 * gp + 3];
          }
          paf[s * 2 + gp] = fr.v;
        }
      }

      __builtin_amdgcn_s_setprio(1);
      #pragma unroll
      for (int dblk = 0; dblk < 4; ++dblk) {
        const int d = dblk * 32 + l31;
        const int vswz = (d & 7) << 4;
        #pragma unroll
        for (int ks = 0; ks < 4; ++ks) {
          bf16x8 vf = *(const bf16x8*)(vbuf + d * 128 + ((ks * 32 + hi16) ^ vswz));
          o[dblk] = __builtin_amdgcn_mfma_f32_32x32x16_bf16(paf[ks], vf, o[dblk], 0, 0, 0);
        }
      }
      __builtin_amdgcn_s_setprio(0);
    }
    __syncthreads();
  }

  const float inv = 1.f / lrun;
  #pragma unroll
  for (int r = 0; r < 16; ++r) {
    const float ir = __shfl(inv, CROW(r, hi));
    const int qrow = qb + CROW(r, hi);
    bf16* orow = O + (bT + qrow) * Cdim + h * 128;
    #pragma unroll
    for (int dblk = 0; dblk < 4; ++dblk)
      orow[dblk * 32 + l31] = __float2bfloat16(o[dblk][r] * ir);
  }
}

extern "C" void kernel_launch(void* const* d_in, const int* in_sizes, int n_in,
                              void* d_out, int out_size, void* d_ws, size_t ws_size,
                              hipStream_t stream) {
  const float* x  = (const float*)d_in[0];
  const float* Wq = (const float*)d_in[1];
  const float* bq = (const float*)d_in[2];
  const float* Wk = (const float*)d_in[3];
  const float* bk = (const float*)d_in[4];
  const float* Wv = (const float*)d_in[5];
  const float* bv = (const float*)d_in[6];
  const float* Wo = (const float*)d_in[7];
  const float* bo = (const float*)d_in[8];

  char* ws = (char*)d_ws;
  const size_t SZ_X  = (size_t)Bdim * Tdim * Cdim * 2;   // 16 MiB
  const size_t SZ_W  = (size_t)Cdim * Cdim * 2;          // 8 MiB
  bf16* x_bf  = (bf16*)(ws);
  bf16* Wq_bf = (bf16*)(ws + SZ_X);                      // [Wq;Wk;Wv] contiguous
  bf16* Wk_bf = (bf16*)(ws + SZ_X + SZ_W);
  bf16* Wv_bf = (bf16*)(ws + SZ_X + 2 * SZ_W);
  bf16* Wo_bf = (bf16*)(ws + SZ_X + 3 * SZ_W);
  bf16* q_bf  = (bf16*)(ws + SZ_X + 4 * SZ_W);
  bf16* k_bf  = (bf16*)(ws + 2 * SZ_X + 4 * SZ_W);
  bf16* v_t   = (bf16*)(ws + 3 * SZ_X + 4 * SZ_W);   // [bh][d][t] transposed V
  bf16* a_bf  = (bf16*)(ws + 4 * SZ_X + 4 * SZ_W);
  float2* cst = (float2*)(ws + 5 * SZ_X + 4 * SZ_W); // [t][32] (cos,sin)

  const int K = Cdim;

  rope_tables_k<<<(Tdim * 32 + 255) / 256, 256, 0, stream>>>(cst);
  cvt_all<<<2048, 256, 0, stream>>>(x, Wq, Wk, Wv, Wo,
                                    x_bf, Wq_bf, Wk_bf, Wv_bf, Wo_bf);

  // QKV: 256x384 tiles -> grid 16x16 = 256 = exactly 1 block/CU
  gemmQKV<<<256, 512, 122880, stream>>>(
      x_bf, Wq_bf, bq, bk, bv, q_bf, k_bf, v_t, cst);

  attn_kernel<<<512, 256, 65536, stream>>>(q_bf, k_bf, v_t, a_bf);

  // Wo: 128x256 8-phase, grid 256 = 1 exact round
  gemmWo<<<256, 512, 98304, stream>>>(
      a_bf, Wo_bf, bo, (float*)d_out, K, 8);
}